// Round 6
// baseline (231.476 us; speedup 1.0000x reference)
//
#include <hip/hip_runtime.h>

// ---------- constants ----------
#define PP    300
#define DD    1024
#define NOUT  604          // (150+1)*4
#define NROWS 19200        // 64*300
// output element offsets (fp32 elements)
#define OFF_PAIR  76800
#define OFF_BBOX  5836800  // 76800 + 64*300*300

typedef unsigned short u16;
typedef __attribute__((ext_vector_type(8))) short bf16x8;
typedef __attribute__((ext_vector_type(4))) float f32x4;

#define GLOBAL_AS __attribute__((address_space(1)))
#define LDS_AS    __attribute__((address_space(3)))

__device__ inline u16 f2bf(float f) {
    unsigned u = __float_as_uint(f);
    return (u16)((u + 0x7fffu + ((u >> 16) & 1u)) >> 16);
}
__device__ inline float dot4(float4 a, float4 b) {
    return fmaf(a.x, b.x, fmaf(a.y, b.y, fmaf(a.z, b.z, a.w * b.w)));
}
__device__ inline float sigmoidf(float z) { return 1.f / (1.f + __expf(-z)); }

// ---------- kernel 1: transpose+pad W_bbox (1024x604 f32) -> Bt (640x1024 bf16) ----------
__global__ void k_transpose(const float* __restrict__ W, u16* __restrict__ Bt) {
    __shared__ float tile[32][33];
    int k0 = blockIdx.x * 32;
    int n0 = blockIdx.y * 32;
    int tx = threadIdx.x;           // 0..31
    int ty = threadIdx.y;           // 0..7
#pragma unroll
    for (int i = 0; i < 4; ++i) {
        int k = k0 + ty + i * 8;
        int n = n0 + tx;
        tile[ty + i * 8][tx] = (n < NOUT) ? W[(size_t)k * NOUT + n] : 0.f;
    }
    __syncthreads();
#pragma unroll
    for (int i = 0; i < 4; ++i) {
        int n = n0 + ty + i * 8;
        int k = k0 + tx;
        Bt[(size_t)n * DD + k] = f2bf(tile[tx][ty + i * 8]);
    }
}

// ---------- kernel 2: v = W_theta @ Wc  (Wc = W_pair[2048:3072]) ----------
__global__ void k_vtheta(const float* __restrict__ Wt, const float* __restrict__ Wpair,
                         float* __restrict__ v) {
    int wave = threadIdx.x >> 6, lane = threadIdx.x & 63;
    int k = blockIdx.x * 4 + wave;                // 0..1023
    const float4* row = (const float4*)(Wt + (size_t)k * DD);
    const float4* wc  = (const float4*)(Wpair + 2 * DD);
    float s = 0.f;
#pragma unroll
    for (int i = 0; i < 4; ++i) s += dot4(row[i * 64 + lane], wc[i * 64 + lane]);
#pragma unroll
    for (int off = 32; off; off >>= 1) s += __shfl_down(s, off, 64);
    if (lane == 0) v[k] = s;
}

// ---------- kernel 3: per-batch scalars ----------
__global__ void k_scalars(const float* __restrict__ relation, const float* __restrict__ subject,
                          const float* __restrict__ obj, const float* __restrict__ btheta,
                          const float* __restrict__ Wpair, const float* __restrict__ bpair,
                          const float* __restrict__ Wcls, const float* __restrict__ bcls,
                          const float* __restrict__ v,
                          float* __restrict__ relt, float* __restrict__ subc,
                          float* __restrict__ objc) {
    __shared__ float red[4];
    int wave = threadIdx.x >> 6, lane = threadIdx.x & 63;
    int b = blockIdx.x;
    const float4* aa;
    const float4* bb;
    if (wave == 0)      { aa = (const float4*)(relation + (size_t)b * DD); bb = (const float4*)v; }
    else if (wave == 1) { aa = (const float4*)(subject + (size_t)b * DD);  bb = (const float4*)(Wcls + DD); }
    else if (wave == 2) { aa = (const float4*)(obj + (size_t)b * DD);      bb = (const float4*)(Wcls + DD); }
    else                { aa = (const float4*)btheta;                      bb = (const float4*)(Wpair + 2 * DD); }
    float s = 0.f;
#pragma unroll
    for (int i = 0; i < 4; ++i) s += dot4(aa[i * 64 + lane], bb[i * 64 + lane]);
#pragma unroll
    for (int off = 32; off; off >>= 1) s += __shfl_down(s, off, 64);
    if (lane == 0) red[wave] = s;
    __syncthreads();
    if (threadIdx.x == 0) {
        relt[b] = red[0] + red[3] + bpair[0];
        subc[b] = red[1] + bcls[0];
        objc[b] = red[2] + bcls[0];
    }
}

// ---------- kernel 4: per-row dots + fp32 x_subj/x_obj outputs ----------
__global__ __launch_bounds__(256) void k_rows(
        const float* __restrict__ x, const float* __restrict__ Wpair,
        const float* __restrict__ Wcls,
        const float* __restrict__ relt, const float* __restrict__ subc,
        const float* __restrict__ objc,
        float* __restrict__ colv, float* __restrict__ rowp,
        float* __restrict__ sarr, float* __restrict__ oarr,
        float* __restrict__ out) {
    int wave = threadIdx.x >> 6, lane = threadIdx.x & 63;
    int r = blockIdx.x * 4 + wave;                // 0..19199
    const float4* xr = (const float4*)(x + (size_t)r * DD);
    const float4* wa = (const float4*)(Wpair);
    const float4* wb = (const float4*)(Wpair + DD);
    const float4* w1 = (const float4*)(Wcls);
    float ca = 0.f, cb = 0.f, cw = 0.f;
#pragma unroll
    for (int i = 0; i < 4; ++i) {
        int idx = i * 64 + lane;
        float4 xv = xr[idx];
        ca += dot4(xv, wa[idx]);
        cb += dot4(xv, wb[idx]);
        cw += dot4(xv, w1[idx]);
    }
#pragma unroll
    for (int off = 32; off; off >>= 1) {
        ca += __shfl_down(ca, off, 64);
        cb += __shfl_down(cb, off, 64);
        cw += __shfl_down(cw, off, 64);
    }
    if (lane == 0) {
        int b = r / 300;
        float s = sigmoidf(cw + subc[b]);
        float o = sigmoidf(cw + objc[b]);
        colv[r] = ca;
        rowp[r] = cb + relt[b];
        sarr[r] = s;
        oarr[r] = o;
        ((float2*)out)[r]         = make_float2(1.f - s, s);   // x_subj pair (fp32)
        ((float2*)out)[NROWS + r] = make_float2(1.f - o, o);   // x_obj pair (fp32)
    }
}

// ---------- kernel 5: pair_score (fp32) ----------
__global__ __launch_bounds__(192) void k_pair(
        const float* __restrict__ rowp, const float* __restrict__ colv,
        const float* __restrict__ sarr, const float* __restrict__ oarr,
        float* __restrict__ pout) {
    int r = blockIdx.x;               // 0..19199
    int b = r / 300;
    int j = threadIdx.x;              // 0..149 (col pair index)
    if (j >= 150) return;
    float rp = rowp[r];
    float ss = sarr[r];
    const float* cb = colv + b * 300;
    const float* ob = oarr + b * 300;
    float p0 = sigmoidf(rp + cb[2 * j])     * ob[2 * j]     * ss;
    float p1 = sigmoidf(rp + cb[2 * j + 1]) * ob[2 * j + 1] * ss;
    ((float2*)(pout + (size_t)r * 300))[j] = make_float2(p0, p1);
}

// ---------- kernel 6: bbox GEMM  C = x(f32->bf16) @ Bt^T + bias  (fp32 out) ----------
#define BKK 64
__global__ __launch_bounds__(256) void k_gemm(
        const float* __restrict__ x, const u16* __restrict__ bt,
        const float* __restrict__ bias, float* __restrict__ out) {
    __shared__ u16 As[128 * BKK] __attribute__((aligned(16)));
    __shared__ u16 Bs[128 * BKK] __attribute__((aligned(16)));

    int bid = blockIdx.x;
    int xcd = bid & 7;
    int rest = bid >> 3;
    int n_t = rest % 5;
    int m_t = (rest / 5) * 8 + xcd;
    if (m_t >= 150) return;

    int tid = threadIdx.x;
    int wave = tid >> 6;
    int lane = tid & 63;
    int wr = wave >> 1, wc = wave & 1;
    int quad = lane >> 4;
    int l16 = lane & 15;

    f32x4 acc[4][4] = {};

    const float* a_base = x  + (size_t)m_t * 128 * DD;
    const u16*   b_base = bt + (size_t)n_t * 128 * DD;
    int s_row = lane >> 3;      // 0..7 (B staging)
    int s_c16 = lane & 7;       // 16B chunk (B staging)
    int arow8 = tid >> 4;       // 0..15 (A staging)
    int acol4 = tid & 15;       // float4 col (A staging)

    for (int k0 = 0; k0 < DD; k0 += BKK) {
        // B: bf16 tile via 16B global_load_lds
#pragma unroll
        for (int q = 0; q < 4; ++q) {
            int rowblk = q * 32 + wave * 8;
            const u16* gb = b_base + (size_t)(rowblk + s_row) * DD + k0 + s_c16 * 8;
            __builtin_amdgcn_global_load_lds((const GLOBAL_AS unsigned int*)gb,
                                             (LDS_AS unsigned int*)(Bs + rowblk * BKK),
                                             16, 0, 0);
        }
        // A: fp32 load, truncate to bf16 via v_perm, ds_write 8B
#pragma unroll
        for (int it = 0; it < 8; ++it) {
            int row = it * 16 + arow8;
            float4 av = *(const float4*)(a_base + (size_t)row * DD + k0 + acol4 * 4);
            unsigned lo = __builtin_amdgcn_perm(__float_as_uint(av.y), __float_as_uint(av.x), 0x07060302u);
            unsigned hi = __builtin_amdgcn_perm(__float_as_uint(av.w), __float_as_uint(av.z), 0x07060302u);
            *(uint2*)(As + row * BKK + acol4 * 4) = make_uint2(lo, hi);
        }
        __syncthreads();
#pragma unroll
        for (int kk = 0; kk < BKK; kk += 32) {
            bf16x8 af[4], bfv[4];
#pragma unroll
            for (int f = 0; f < 4; ++f) {
                int m = wr * 64 + f * 16 + l16;
                af[f] = *(const bf16x8*)(As + m * BKK + kk + quad * 8);
                int n = wc * 64 + f * 16 + l16;
                bfv[f] = *(const bf16x8*)(Bs + n * BKK + kk + quad * 8);
            }
#pragma unroll
            for (int fi = 0; fi < 4; ++fi)
#pragma unroll
                for (int fj = 0; fj < 4; ++fj)
                    acc[fi][fj] = __builtin_amdgcn_mfma_f32_16x16x32_bf16(
                        af[fi], bfv[fj], acc[fi][fj], 0, 0, 0);
        }
        __syncthreads();
    }

    // epilogue: add bias, mask col<604, store fp32
#pragma unroll
    for (int fj = 0; fj < 4; ++fj) {
        int col = n_t * 128 + wc * 64 + fj * 16 + l16;
        if (col < NOUT) {
            float bia = bias[col];
#pragma unroll
            for (int fi = 0; fi < 4; ++fi) {
#pragma unroll
                for (int rg = 0; rg < 4; ++rg) {
                    int row = m_t * 128 + wr * 64 + fi * 16 + quad * 4 + rg;
                    out[(size_t)row * NOUT + col] = acc[fi][fj][rg] + bia;
                }
            }
        }
    }
}

extern "C" void kernel_launch(void* const* d_in, const int* in_sizes, int n_in,
                              void* d_out, int out_size, void* d_ws, size_t ws_size,
                              hipStream_t stream) {
    // ---- input binding by element counts (proven equivalent to dict order) ----
    const void* P[12] = {};
    int sv[3] = {-1, -1, -1}; int nsv = 0;
    int sc[2] = {-1, -1};     int nsc = 0;
    for (int i = 0; i < n_in; ++i) {
        switch (in_sizes[i]) {
            case 19660800: P[0]  = d_in[i]; break;
            case 65536:    if (nsv < 3) sv[nsv++] = i; break;
            case 1048576:  P[4]  = d_in[i]; break;
            case 1024:     P[5]  = d_in[i]; break;
            case 3072:     P[6]  = d_in[i]; break;
            case 1:        if (nsc < 2) sc[nsc++] = i; break;
            case 2048:     P[8]  = d_in[i]; break;
            case 618496:   P[10] = d_in[i]; break;
            case 604:      P[11] = d_in[i]; break;
            default: break;
        }
    }
    bool alpha = (n_in == 12 && in_sizes[0] == 618496);
    if (alpha) {
        P[2] = d_in[sv[0]]; P[3] = d_in[sv[1]]; P[1] = d_in[sv[2]];
        P[9] = d_in[sc[0]]; P[7] = d_in[sc[1]];
    } else {
        P[1] = d_in[sv[0]]; P[2] = d_in[sv[1]]; P[3] = d_in[sv[2]];
        P[7] = d_in[sc[0]]; P[9] = d_in[sc[1]];
    }
    const float* x        = (const float*)P[0];
    const float* subject  = (const float*)P[1];
    const float* obj      = (const float*)P[2];
    const float* relation = (const float*)P[3];
    const float* W_theta  = (const float*)P[4];
    const float* b_theta  = (const float*)P[5];
    const float* W_pair   = (const float*)P[6];
    const float* b_pair   = (const float*)P[7];
    const float* W_cls    = (const float*)P[8];
    const float* b_cls    = (const float*)P[9];
    const float* W_bbox   = (const float*)P[10];
    const float* b_bbox   = (const float*)P[11];
    float* out = (float*)d_out;

    // ws layout (~1.62 MB)
    char* ws = (char*)d_ws;
    float* v    = (float*)(ws + 0);         // 1024 f32
    float* relt = (float*)(ws + 4096);      // 64 f32
    float* subc = (float*)(ws + 4352);      // 64 f32
    float* objc = (float*)(ws + 4608);      // 64 f32
    float* colv = (float*)(ws + 4864);      // 19200 f32
    float* rowp = (float*)(ws + 81664);     // 19200 f32
    float* sarr = (float*)(ws + 158464);    // 19200 f32
    float* oarr = (float*)(ws + 235264);    // 19200 f32 (end 312,064)
    u16*   Bt   = (u16*)(ws + 312064);      // 640*1024 bf16 = 1,310,720 B

    k_transpose<<<dim3(32, 20), dim3(32, 8), 0, stream>>>(W_bbox, Bt);
    k_vtheta<<<256, 256, 0, stream>>>(W_theta, W_pair, v);
    k_scalars<<<64, 256, 0, stream>>>(relation, subject, obj, b_theta, W_pair, b_pair,
                                      W_cls, b_cls, v, relt, subc, objc);
    k_rows<<<4800, 256, 0, stream>>>(x, W_pair, W_cls, relt, subc, objc,
                                     colv, rowp, sarr, oarr, out);
    k_pair<<<19200, 192, 0, stream>>>(rowp, colv, sarr, oarr, out + OFF_PAIR);
    k_gemm<<<760, 256, 0, stream>>>(x, Bt, b_bbox, out + OFF_BBOX);
}